// Round 8
// baseline (6959.385 us; speedup 1.0000x reference)
//
#include <hip/hip_runtime.h>
#include <hip/hip_fp16.h>

// B=1024, T=512, H=128, G=4H=512, IN=1
// 256 blocks x 512 thr; block owns 4 rows; wave w owns units [16w,16w+16).
// Merged phase: iter i does L1(i) and L2(i-1); ONE barrier per iter.
// A-tiles use DUPLICATE-ROW mapping (A row i = real row i>>2) so C reg 0
// = the lane's own cell -> no gate redistribution needed at all.
#define TT 512
#define RR 4

using f16   = _Float16;
using f16x8 = __attribute__((ext_vector_type(8))) _Float16;
using f32x4 = __attribute__((ext_vector_type(4))) float;

__device__ __forceinline__ float sigm(float x) {
    return __builtin_amdgcn_rcpf(1.0f + __builtin_amdgcn_exp2f(x * -1.44269504f));
}
__device__ __forceinline__ float tanh_(float x) {
    return 1.0f - 2.0f * __builtin_amdgcn_rcpf(1.0f + __builtin_amdgcn_exp2f(x * 2.88539008f));
}
__device__ __forceinline__ f16x8 cvt8(const float* p) {
    float4 a = ((const float4*)p)[0], b = ((const float4*)p)[1];
    return f16x8{(f16)a.x,(f16)a.y,(f16)a.z,(f16)a.w,
                 (f16)b.x,(f16)b.y,(f16)b.z,(f16)b.w};
}
// keep weight fragments loop-carried in VGPRs (prevent remat/sinking)
#define PIN4(a,b,c,d) asm volatile("" : "+v"(a), "+v"(b), "+v"(c), "+v"(d))

// LDS (dynamic 98304 B -> forces 1 block/CU):
//   [0,2048)     h1 mailbox: 2 x [4 rows][256 B] f16, chunk-swizzled ^(row<<5)
//   [2048,4096)  h2 mailbox: same
//   [4096,4224)  red[32] f32
__global__ __launch_bounds__(512, 2) void lstm2_dup(
    const float* __restrict__ x,
    const float* __restrict__ Wih1,
    const float* __restrict__ Whh1,
    const float* __restrict__ bih1,
    const float* __restrict__ bhh1,
    const float* __restrict__ Wih2,
    const float* __restrict__ Whh2,
    const float* __restrict__ bih2,
    const float* __restrict__ bhh2,
    const float* __restrict__ Wl,
    const float* __restrict__ bl,
    float* __restrict__ out)
{
    extern __shared__ char smem[];
    char*  const h1m = smem;            // [2][1024]
    char*  const h2m = smem + 2048;     // [2][1024]
    float* const red = (float*)(smem + 4096);

    const int tid  = threadIdx.x;
    const int w    = tid >> 6;
    const int lane = tid & 63;
    const int r    = lane & 15;
    const int q    = lane >> 4;
    const int rowbase = blockIdx.x * RR;
    const int u    = w * 16 + r;        // owned unit; cell = (row q, unit u)

    // zero both mailboxes (4096 B)
    *(float2*)(smem + tid * 8) = float2{0.f, 0.f};

    // per-cell constants
    float b1o[4], b2o[4], w1o[4];
    #pragma unroll
    for (int g = 0; g < 4; ++g) {
        int n = g * 128 + u;
        b1o[g] = bih1[n] + bhh1[n];
        b2o[g] = bih2[n] + bhh2[n];
        w1o[g] = Wih1[n];
    }
    const float wlv = Wl[u];
    const float bl0 = bl[0];

    // ALL weight B-fragments in registers (48 frags = 192 VGPRs), plain cols
    f16x8 wr1[4][4], w2i[4][4], w2h[4][4];
    #pragma unroll
    for (int g = 0; g < 4; ++g) {
        int n = g * 128 + u;
        #pragma unroll
        for (int kt = 0; kt < 4; ++kt) {
            int k0 = kt * 32 + q * 8;
            wr1[g][kt] = cvt8(Whh1 + n * 128 + k0);
            w2i[g][kt] = cvt8(Wih2 + n * 128 + k0);
            w2h[g][kt] = cvt8(Whh2 + n * 128 + k0);
        }
    }

    // A-frag offsets: A row r <- mailbox row (r>>2); chunk ^(row<<5) swizzle
    const int a4 = r >> 2;
    int afm[4];
    #pragma unroll
    for (int kt = 0; kt < 4; ++kt)
        afm[kt] = a4 * 256 + ((kt * 64 + q * 16) ^ (a4 << 5));
    // h-write: even-r lanes pack units (u, u+1) as b32 at row q (same swizzle)
    const int hwb = q * 256 + ((w * 32 + 2 * r) ^ (q << 5));

    float c1 = 0.f, c2 = 0.f, h2fin = 0.f;

    __syncthreads();

    for (int i = 0; i <= TT; ++i) {
        const int p = i & 1, pp = p ^ 1;
        const bool doL1 = (i < TT), doL2 = (i > 0);

        // pin weights: loop-carried, cannot be rematerialized inside the loop
        #pragma unroll
        for (int g = 0; g < 4; ++g) {
            PIN4(wr1[g][0], wr1[g][1], wr1[g][2], wr1[g][3]);
            PIN4(w2i[g][0], w2i[g][1], w2i[g][2], w2i[g][3]);
            PIN4(w2h[g][0], w2h[g][1], w2h[g][2], w2h[g][3]);
        }

        // A-fragments: h1(i-1) shared by L1 and L2-input; h2(i-2) for L2
        f16x8 a1[4], ah2[4];
        #pragma unroll
        for (int kt = 0; kt < 4; ++kt)
            a1[kt] = *(const f16x8*)(h1m + pp * 1024 + afm[kt]);
        if (doL2) {
            #pragma unroll
            for (int kt = 0; kt < 4; ++kt)
                ah2[kt] = *(const f16x8*)(h2m + p * 1024 + afm[kt]);
        }
        const float xv = doL1 ? x[(rowbase + q) * TT + i] : 0.f;

        f32x4 acc1[4] = {{0,0,0,0},{0,0,0,0},{0,0,0,0},{0,0,0,0}};
        f32x4 acc2[4] = {{0,0,0,0},{0,0,0,0},{0,0,0,0},{0,0,0,0}};
        if (doL1) {
            #pragma unroll
            for (int g = 0; g < 4; ++g)
                #pragma unroll
                for (int kt = 0; kt < 4; ++kt)
                    acc1[g] = __builtin_amdgcn_mfma_f32_16x16x32_f16(
                        a1[kt], wr1[g][kt], acc1[g], 0, 0, 0);
        }
        if (doL2) {
            #pragma unroll
            for (int g = 0; g < 4; ++g) {
                #pragma unroll
                for (int kt = 0; kt < 4; ++kt)
                    acc2[g] = __builtin_amdgcn_mfma_f32_16x16x32_f16(
                        a1[kt], w2i[g][kt], acc2[g], 0, 0, 0);
                #pragma unroll
                for (int kt = 0; kt < 4; ++kt)
                    acc2[g] = __builtin_amdgcn_mfma_f32_16x16x32_f16(
                        ah2[kt], w2h[g][kt], acc2[g], 0, 0, 0);
            }
        }

        // ---- gate math: acc reg 0 IS this lane's cell (row q, unit u) ----
        if (doL1) {
            float p0 = acc1[0][0] + fmaf(xv, w1o[0], b1o[0]);
            float p1 = acc1[1][0] + fmaf(xv, w1o[1], b1o[1]);
            float p2 = acc1[2][0] + fmaf(xv, w1o[2], b1o[2]);
            float p3 = acc1[3][0] + fmaf(xv, w1o[3], b1o[3]);
            float gi = sigm(p0), gf = sigm(p1), gg = tanh_(p2), go = sigm(p3);
            c1 = gf * c1 + gi * gg;
            float hv = go * tanh_(c1);
            float hn = __shfl_xor(hv, 1);
            if ((r & 1) == 0) {
                union { f16 h[2]; unsigned uu; } pk;
                pk.h[0] = (f16)hv; pk.h[1] = (f16)hn;
                *(unsigned*)(h1m + p * 1024 + hwb) = pk.uu;
            }
        }
        if (doL2) {
            float p0 = acc2[0][0] + b2o[0];
            float p1 = acc2[1][0] + b2o[1];
            float p2 = acc2[2][0] + b2o[2];
            float p3 = acc2[3][0] + b2o[3];
            float gi = sigm(p0), gf = sigm(p1), gg = tanh_(p2), go = sigm(p3);
            c2 = gf * c2 + gi * gg;
            float hv = go * tanh_(c2);
            h2fin = hv;
            float hn = __shfl_xor(hv, 1);
            if ((r & 1) == 0) {
                union { f16 h[2]; unsigned uu; } pk;
                pk.h[0] = (f16)hv; pk.h[1] = (f16)hn;
                *(unsigned*)(h2m + pp * 1024 + hwb) = pk.uu;
            }
        }

        __syncthreads();   // the ONE barrier per iteration
    }

    // ---- out[row q] = sum_u h2fin * Wl[u] + bl ----
    float v = h2fin * wlv;
    v += __shfl_xor(v, 1);
    v += __shfl_xor(v, 2);
    v += __shfl_xor(v, 4);
    v += __shfl_xor(v, 8);                // lane r==0 holds wave partial for row q
    if (r == 0) red[q * 8 + w] = v;
    __syncthreads();
    if (tid < RR) {
        float a = bl0;
        #pragma unroll
        for (int s = 0; s < 8; ++s) a += red[tid * 8 + s];
        out[rowbase + tid] = a;
    }
}

extern "C" void kernel_launch(void* const* d_in, const int* in_sizes, int n_in,
                              void* d_out, int out_size, void* d_ws, size_t ws_size,
                              hipStream_t stream) {
    const float* x    = (const float*)d_in[0];
    const float* Wih1 = (const float*)d_in[1];
    const float* Whh1 = (const float*)d_in[2];
    const float* bih1 = (const float*)d_in[3];
    const float* bhh1 = (const float*)d_in[4];
    const float* Wih2 = (const float*)d_in[5];
    const float* Whh2 = (const float*)d_in[6];
    const float* bih2 = (const float*)d_in[7];
    const float* bhh2 = (const float*)d_in[8];
    const float* Wl   = (const float*)d_in[9];
    const float* bl   = (const float*)d_in[10];
    float* out = (float*)d_out;

    static constexpr size_t SMEM = 98304;   // forces 1 block/CU
    hipFuncSetAttribute(reinterpret_cast<const void*>(&lstm2_dup),
                        hipFuncAttributeMaxDynamicSharedMemorySize, (int)SMEM);

    lstm2_dup<<<dim3(256), dim3(512), SMEM, stream>>>(
        x, Wih1, Whh1, bih1, bhh1, Wih2, Whh2, bih2, bhh2, Wl, bl, out);
}

// Round 10
// 788.057 us; speedup vs baseline: 8.8311x; 8.8311x over previous
//
#include <hip/hip_runtime.h>
#include <hip/hip_fp16.h>

// B=1024, T=512, H=128, G=4H=512, IN=1
// 256 blocks x 512 thr; block owns 4 rows; wave w owns units [16w,16w+16).
// Merged phase: iter i does L1(i) and L2(i-1); ONE barrier per iter.
// A-tiles use DUPLICATE-ROW mapping (A row i = real row i>>2) so C reg 0
// = the lane's own cell -> no gate redistribution needed at all.
// Weight fragments deliberately UNPINNED: compiler parks them in AGPRs
// (unified file; MFMA reads B from AGPR) -- R8's "+v" pins forced arch-VGPR
// allocation and caused 21.5 GB/dispatch of scratch spill.
#define TT 512
#define RR 4

using f16   = _Float16;
using f16x8 = __attribute__((ext_vector_type(8))) _Float16;
using f32x4 = __attribute__((ext_vector_type(4))) float;

__device__ __forceinline__ float sigm(float x) {
    return __builtin_amdgcn_rcpf(1.0f + __builtin_amdgcn_exp2f(x * -1.44269504f));
}
__device__ __forceinline__ float tanh_(float x) {
    return 1.0f - 2.0f * __builtin_amdgcn_rcpf(1.0f + __builtin_amdgcn_exp2f(x * 2.88539008f));
}
__device__ __forceinline__ f16x8 cvt8(const float* p) {
    float4 a = ((const float4*)p)[0], b = ((const float4*)p)[1];
    return f16x8{(f16)a.x,(f16)a.y,(f16)a.z,(f16)a.w,
                 (f16)b.x,(f16)b.y,(f16)b.z,(f16)b.w};
}

// LDS (dynamic 98304 B -> forces 1 block/CU so grid=256 covers all CUs):
//   [0,2048)     h1 mailbox: 2 x [4 rows][256 B] f16, chunk-swizzled ^(row<<5)
//   [2048,4096)  h2 mailbox: same
//   [4096,4224)  red[32] f32
__global__ __launch_bounds__(512, 2) void lstm2_dup(
    const float* __restrict__ x,
    const float* __restrict__ Wih1,
    const float* __restrict__ Whh1,
    const float* __restrict__ bih1,
    const float* __restrict__ bhh1,
    const float* __restrict__ Wih2,
    const float* __restrict__ Whh2,
    const float* __restrict__ bih2,
    const float* __restrict__ bhh2,
    const float* __restrict__ Wl,
    const float* __restrict__ bl,
    float* __restrict__ out)
{
    extern __shared__ char smem[];
    char*  const h1m = smem;            // [2][1024]
    char*  const h2m = smem + 2048;     // [2][1024]
    float* const red = (float*)(smem + 4096);

    const int tid  = threadIdx.x;
    const int w    = tid >> 6;
    const int lane = tid & 63;
    const int r    = lane & 15;
    const int q    = lane >> 4;
    const int rowbase = blockIdx.x * RR;
    const int u    = w * 16 + r;        // owned unit; cell = (row q, unit u)

    // zero both mailboxes (4096 B)
    *(float2*)(smem + tid * 8) = float2{0.f, 0.f};

    // per-cell constants
    float b1o[4], b2o[4], w1o[4];
    #pragma unroll
    for (int g = 0; g < 4; ++g) {
        int n = g * 128 + u;
        b1o[g] = bih1[n] + bhh1[n];
        b2o[g] = bih2[n] + bhh2[n];
        w1o[g] = Wih1[n];
    }
    const float wlv = Wl[u];
    const float bl0 = bl[0];

    // ALL weight B-fragments in registers/AGPRs (48 frags), plain cols
    f16x8 wr1[4][4], w2i[4][4], w2h[4][4];
    #pragma unroll
    for (int g = 0; g < 4; ++g) {
        int n = g * 128 + u;
        #pragma unroll
        for (int kt = 0; kt < 4; ++kt) {
            int k0 = kt * 32 + q * 8;
            wr1[g][kt] = cvt8(Whh1 + n * 128 + k0);
            w2i[g][kt] = cvt8(Wih2 + n * 128 + k0);
            w2h[g][kt] = cvt8(Whh2 + n * 128 + k0);
        }
    }

    // A-frag offsets: A row r <- mailbox row (r>>2); chunk ^(row<<5) swizzle
    const int a4 = r >> 2;
    int afm[4];
    #pragma unroll
    for (int kt = 0; kt < 4; ++kt)
        afm[kt] = a4 * 256 + ((kt * 64 + q * 16) ^ (a4 << 5));
    // h-write: even-r lanes pack units (u, u+1) as b32 at row q (same swizzle)
    const int hwb = q * 256 + ((w * 32 + 2 * r) ^ (q << 5));

    float c1 = 0.f, c2 = 0.f, h2fin = 0.f;

    __syncthreads();

    for (int i = 0; i <= TT; ++i) {
        const int p = i & 1, pp = p ^ 1;
        const bool doL1 = (i < TT), doL2 = (i > 0);

        // A-fragments: h1(i-1) shared by L1 and L2-input; h2(i-2) for L2
        f16x8 a1[4], ah2[4];
        #pragma unroll
        for (int kt = 0; kt < 4; ++kt)
            a1[kt] = *(const f16x8*)(h1m + pp * 1024 + afm[kt]);
        if (doL2) {
            #pragma unroll
            for (int kt = 0; kt < 4; ++kt)
                ah2[kt] = *(const f16x8*)(h2m + p * 1024 + afm[kt]);
        }
        const float xv = doL1 ? x[(rowbase + q) * TT + i] : 0.f;

        f32x4 acc1[4] = {{0,0,0,0},{0,0,0,0},{0,0,0,0},{0,0,0,0}};
        f32x4 acc2[4] = {{0,0,0,0},{0,0,0,0},{0,0,0,0},{0,0,0,0}};
        if (doL1) {
            #pragma unroll
            for (int g = 0; g < 4; ++g)
                #pragma unroll
                for (int kt = 0; kt < 4; ++kt)
                    acc1[g] = __builtin_amdgcn_mfma_f32_16x16x32_f16(
                        a1[kt], wr1[g][kt], acc1[g], 0, 0, 0);
        }
        if (doL2) {
            #pragma unroll
            for (int g = 0; g < 4; ++g) {
                #pragma unroll
                for (int kt = 0; kt < 4; ++kt)
                    acc2[g] = __builtin_amdgcn_mfma_f32_16x16x32_f16(
                        a1[kt], w2i[g][kt], acc2[g], 0, 0, 0);
                #pragma unroll
                for (int kt = 0; kt < 4; ++kt)
                    acc2[g] = __builtin_amdgcn_mfma_f32_16x16x32_f16(
                        ah2[kt], w2h[g][kt], acc2[g], 0, 0, 0);
            }
        }

        // ---- gate math: acc reg 0 IS this lane's cell (row q, unit u) ----
        if (doL1) {
            float p0 = acc1[0][0] + fmaf(xv, w1o[0], b1o[0]);
            float p1 = acc1[1][0] + fmaf(xv, w1o[1], b1o[1]);
            float p2 = acc1[2][0] + fmaf(xv, w1o[2], b1o[2]);
            float p3 = acc1[3][0] + fmaf(xv, w1o[3], b1o[3]);
            float gi = sigm(p0), gf = sigm(p1), gg = tanh_(p2), go = sigm(p3);
            c1 = gf * c1 + gi * gg;
            float hv = go * tanh_(c1);
            float hn = __shfl_xor(hv, 1);
            if ((r & 1) == 0) {
                union { f16 h[2]; unsigned uu; } pk;
                pk.h[0] = (f16)hv; pk.h[1] = (f16)hn;
                *(unsigned*)(h1m + p * 1024 + hwb) = pk.uu;
            }
        }
        if (doL2) {
            float p0 = acc2[0][0] + b2o[0];
            float p1 = acc2[1][0] + b2o[1];
            float p2 = acc2[2][0] + b2o[2];
            float p3 = acc2[3][0] + b2o[3];
            float gi = sigm(p0), gf = sigm(p1), gg = tanh_(p2), go = sigm(p3);
            c2 = gf * c2 + gi * gg;
            float hv = go * tanh_(c2);
            h2fin = hv;
            float hn = __shfl_xor(hv, 1);
            if ((r & 1) == 0) {
                union { f16 h[2]; unsigned uu; } pk;
                pk.h[0] = (f16)hv; pk.h[1] = (f16)hn;
                *(unsigned*)(h2m + pp * 1024 + hwb) = pk.uu;
            }
        }

        __syncthreads();   // the ONE barrier per iteration
    }

    // ---- out[row q] = sum_u h2fin * Wl[u] + bl ----
    float v = h2fin * wlv;
    v += __shfl_xor(v, 1);
    v += __shfl_xor(v, 2);
    v += __shfl_xor(v, 4);
    v += __shfl_xor(v, 8);                // lane r==0 holds wave partial for row q
    if (r == 0) red[q * 8 + w] = v;
    __syncthreads();
    if (tid < RR) {
        float a = bl0;
        #pragma unroll
        for (int s = 0; s < 8; ++s) a += red[tid * 8 + s];
        out[rowbase + tid] = a;
    }
}

extern "C" void kernel_launch(void* const* d_in, const int* in_sizes, int n_in,
                              void* d_out, int out_size, void* d_ws, size_t ws_size,
                              hipStream_t stream) {
    const float* x    = (const float*)d_in[0];
    const float* Wih1 = (const float*)d_in[1];
    const float* Whh1 = (const float*)d_in[2];
    const float* bih1 = (const float*)d_in[3];
    const float* bhh1 = (const float*)d_in[4];
    const float* Wih2 = (const float*)d_in[5];
    const float* Whh2 = (const float*)d_in[6];
    const float* bih2 = (const float*)d_in[7];
    const float* bhh2 = (const float*)d_in[8];
    const float* Wl   = (const float*)d_in[9];
    const float* bl   = (const float*)d_in[10];
    float* out = (float*)d_out;

    static constexpr size_t SMEM = 98304;   // forces 1 block/CU
    hipFuncSetAttribute(reinterpret_cast<const void*>(&lstm2_dup),
                        hipFuncAttributeMaxDynamicSharedMemorySize, (int)SMEM);

    lstm2_dup<<<dim3(256), dim3(512), SMEM, stream>>>(
        x, Wih1, Whh1, bih1, bhh1, Wih2, Whh2, bih2, bhh2, Wl, bl, out);
}